// Round 7
// baseline (385.828 us; speedup 1.0000x reference)
//
#include <hip/hip_runtime.h>
#include <hip/hip_fp16.h>

#define N_USERS 100000
#define N_ITEMS 50000
#define N_TOT   150000
#define DIM     64
#define E_EDGES 3000000
#define NP1     (N_TOT + 1)
#define NB1     586          // ceil(150000/256) coarse buckets (row >> 8)
#define EPB     4096         // edges per block in binning kernels
#define SEDGE_MAX 4100000    // E + 7*N_TOT = 4.05M padded worst case

__device__ __forceinline__ __half2 h2_from_int(int x) {
    union { int i; __half2 h; } u; u.i = x; return u.h;
}
__device__ __forceinline__ int int_from_h2(__half2 h) {
    union { int i; __half2 h; } u; u.h = h; return u.i;
}

// ---------------- init: b0 = fp16(emb) ----------------

__global__ void init_kernel(const float* __restrict__ user_emb,
                            const float* __restrict__ item_emb,
                            __half2* __restrict__ b0) {
    int i = blockIdx.x * blockDim.x + threadIdx.x;
    const int total4 = N_TOT * DIM / 4;
    if (i < total4) {
        int base = i * 4;
        float4 v = (base < N_USERS * DIM)
                     ? reinterpret_cast<const float4*>(user_emb)[i]
                     : reinterpret_cast<const float4*>(item_emb)[(base - N_USERS * DIM) >> 2];
        b0[i * 2]     = __floats2half2_rn(v.x, v.y);
        b0[i * 2 + 1] = __floats2half2_rn(v.z, v.w);
    }
}

__global__ void zero_int_kernel(int* __restrict__ p, int n) {
    int i = blockIdx.x * blockDim.x + threadIdx.x;
    if (i < n) p[i] = 0;
}

// ---------------- CSR build (padded rows, two-level counting sort) ----------------

__global__ void rowhist_kernel(const int* __restrict__ rows, int* __restrict__ rowdeg) {
    int e = blockIdx.x * blockDim.x + threadIdx.x;
    if (e < E_EDGES) atomicAdd(&rowdeg[rows[e]], 1);
}

// per-bucket raw and padded totals
__global__ __launch_bounds__(256) void bucketsum_kernel(const int* __restrict__ rowdeg,
                                                        int* __restrict__ bktraw,
                                                        int* __restrict__ bktpad) {
    int b = blockIdx.x, t = threadIdx.x;
    int r = b * 256 + t;
    int d = (r < N_TOT) ? rowdeg[r] : 0;
    int pd = (d + 7) & ~7;
    __shared__ int sr[256], sp[256];
    sr[t] = d; sp[t] = pd;
    __syncthreads();
    for (int off = 128; off > 0; off >>= 1) {
        if (t < off) { sr[t] += sr[t + off]; sp[t] += sp[t + off]; }
        __syncthreads();
    }
    if (t == 0) { bktraw[b] = sr[0]; bktpad[b] = sp[0]; }
}

// exclusive scans of raw (tmp windows) and padded (sedge windows) bucket sizes
__global__ __launch_bounds__(256) void bscan2_kernel(const int* __restrict__ bktraw,
                                                     const int* __restrict__ bktpad,
                                                     int* __restrict__ bstart,
                                                     int* __restrict__ pbstart) {
    __shared__ int psum[256];
    int t = threadIdx.x;
    for (int pass = 0; pass < 2; ++pass) {
        const int* src = pass ? bktpad : bktraw;
        int* dst = pass ? pbstart : bstart;
        int i0 = t * 3;
        int s0 = (i0     < NB1) ? src[i0]     : 0;
        int s1 = (i0 + 1 < NB1) ? src[i0 + 1] : 0;
        int s2 = (i0 + 2 < NB1) ? src[i0 + 2] : 0;
        int tsum = s0 + s1 + s2;
        psum[t] = tsum;
        __syncthreads();
        for (int off = 1; off < 256; off <<= 1) {
            int x = (t >= off) ? psum[t - off] : 0;
            __syncthreads();
            psum[t] += x;
            __syncthreads();
        }
        int excl = psum[t] - tsum;
        if (i0     < NB1) dst[i0]     = excl;
        if (i0 + 1 < NB1) dst[i0 + 1] = excl + s0;
        if (i0 + 2 < NB1) dst[i0 + 2] = excl + s0 + s1;
        if (t == 255) dst[NB1] = psum[255];
        __syncthreads();
    }
}

// row_ptr from padded within-bucket scan; zero-fill pad slots in sedge
__global__ __launch_bounds__(256) void rowptr_kernel(const int* __restrict__ rowdeg,
                                                     const int* __restrict__ pbstart,
                                                     int* __restrict__ row_ptr,
                                                     int2* __restrict__ sedge) {
    int b = blockIdx.x, t = threadIdx.x;
    int r = b * 256 + t;
    int d = (r < N_TOT) ? rowdeg[r] : 0;
    int pd = (d + 7) & ~7;
    __shared__ int scn[256];
    scn[t] = pd;
    __syncthreads();
    for (int off = 1; off < 256; off <<= 1) {
        int x = (t >= off) ? scn[t - off] : 0;
        __syncthreads();
        scn[t] += x;
        __syncthreads();
    }
    int excl = scn[t] - pd;
    int rp = pbstart[b] + excl;
    if (r <= N_TOT) row_ptr[r] = rp;
    if (r < N_TOT) {
        int2* spad = sedge + rp + d;
        for (int i = d; i < pd; ++i) *spad++ = make_int2(0, 0);
    }
}

// bin edges into coarse buckets (LDS-staged, coalesced run write-out)
__global__ __launch_bounds__(256) void bin_kernel(const int* __restrict__ rows,
                                                  const int* __restrict__ cols,
                                                  const float* __restrict__ vals,
                                                  const int* __restrict__ bstart,
                                                  int* __restrict__ fill1,
                                                  int2* __restrict__ tmp) {
    __shared__ int sw0[EPB];
    __shared__ int sw1[EPB];
    __shared__ unsigned short sbkt[EPB];
    __shared__ int hist[NB1];
    __shared__ int sstart[NB1];
    __shared__ int gbase[NB1];
    __shared__ int cursor[NB1];
    __shared__ int psum[256];

    int e0 = blockIdx.x * EPB;
    int cnt = min(EPB, E_EDGES - e0);

    for (int b = threadIdx.x; b < NB1; b += 256) hist[b] = 0;
    __syncthreads();

    int r[16], c[16]; float v[16];
#pragma unroll
    for (int k = 0; k < 16; ++k) {
        int i = threadIdx.x + k * 256;   // coalesced
        r[k] = -1;
        if (i < cnt) {
            int e = e0 + i;
            r[k] = rows[e];
            c[k] = cols[e];
            v[k] = vals[e];
            atomicAdd(&hist[r[k] >> 8], 1);
        }
    }
    __syncthreads();

    int t = threadIdx.x;
    int i0 = t * 3;
    int s0 = (i0     < NB1) ? hist[i0]     : 0;
    int s1 = (i0 + 1 < NB1) ? hist[i0 + 1] : 0;
    int s2 = (i0 + 2 < NB1) ? hist[i0 + 2] : 0;
    int tsum = s0 + s1 + s2;
    psum[t] = tsum;
    __syncthreads();
    for (int off = 1; off < 256; off <<= 1) {
        int x = (t >= off) ? psum[t - off] : 0;
        __syncthreads();
        psum[t] += x;
        __syncthreads();
    }
    int excl = psum[t] - tsum;
    if (i0     < NB1) sstart[i0]     = excl;
    if (i0 + 1 < NB1) sstart[i0 + 1] = excl + s0;
    if (i0 + 2 < NB1) sstart[i0 + 2] = excl + s0 + s1;
    __syncthreads();

    for (int b = threadIdx.x; b < NB1; b += 256) {
        int h = hist[b];
        gbase[b] = (h > 0) ? (bstart[b] + atomicAdd(&fill1[b], h)) : 0;
        cursor[b] = sstart[b];
    }
    __syncthreads();

#pragma unroll
    for (int k = 0; k < 16; ++k) {
        if (r[k] >= 0) {
            int b = r[k] >> 8;
            int p = atomicAdd(&cursor[b], 1);
            sw0[p] = ((r[k] & 0xFF) << 24) | c[k];
            sw1[p] = int_from_h2(__floats2half2_rn(v[k], v[k]));  // duplicated half2 val
            sbkt[p] = (unsigned short)b;
        }
    }
    __syncthreads();

    for (int i = threadIdx.x; i < cnt; i += 256) {
        int b = sbkt[i];
        int dest = gbase[b] + (i - sstart[b]);
        tmp[dest] = make_int2(sw0[i], sw1[i]);
    }
}

// per-bucket scatter to padded positions; cursors preloaded from row_ptr
__global__ __launch_bounds__(256) void sort_kernel(const int2* __restrict__ tmp,
                                                   const int* __restrict__ bstart,
                                                   const int* __restrict__ row_ptr,
                                                   int2* __restrict__ sedge) {
    int b = blockIdx.x;
    int beg = bstart[b], end = bstart[b + 1];
    __shared__ int cursor[256];
    int t = threadIdx.x;
    int r = b * 256 + t;
    cursor[t] = (r < N_TOT) ? row_ptr[r] : 0;
    __syncthreads();
    for (int i = beg + t; i < end; i += 256) {
        int2 rec = tmp[i];
        int lr = ((unsigned)rec.x) >> 24;
        int p = atomicAdd(&cursor[lr], 1);
        sedge[p] = make_int2(rec.x & 0xFFFFFF, rec.y);
    }
}

// ---------------- SpMM: 2 rows/wave, direct uniform edge loads, pk_fma_f16 ----------------
// Rows padded to multiple of 8 edges (pad col=0,val=0): inner loop has no masking.
// Per group of 8 edges: 4x int4 uniform loads + 8 gathers + 8 hfma2 + flush.

__global__ __launch_bounds__(256) void spmm2_kernel(const int* __restrict__ row_ptr,
                                                    const int2* __restrict__ sedge,
                                                    const __half2* __restrict__ src,
                                                    __half2* __restrict__ dst,
                                                    const __half2* __restrict__ c0,
                                                    const __half2* __restrict__ c1,
                                                    float* __restrict__ acc,
                                                    int last) {
    int wid2 = (blockIdx.x * blockDim.x + threadIdx.x) >> 6;
    int lane = threadIdx.x & 63;
    int sub = lane & 31;
    int row = wid2 * 2 + (lane >> 5);
    if (row >= N_TOT) return;
    int beg = row_ptr[row];
    int ng  = (row_ptr[row + 1] - beg) >> 3;   // groups of 8 (exact: padded)
    const int4* ep = reinterpret_cast<const int4*>(sedge + beg);
    float s0 = 0.0f, s1 = 0.0f;
    const __half2 z2 = __floats2half2_rn(0.0f, 0.0f);
    for (int g = 0; g < ng; ++g) {
        int4 e0 = ep[0]; int4 e1 = ep[1]; int4 e2 = ep[2]; int4 e3 = ep[3];
        ep += 4;
        __half2 a0 = z2, a1 = z2;
        a0 = __hfma2(h2_from_int(e0.y), src[(unsigned)e0.x * 32u + sub], a0);
        a1 = __hfma2(h2_from_int(e0.w), src[(unsigned)e0.z * 32u + sub], a1);
        a0 = __hfma2(h2_from_int(e1.y), src[(unsigned)e1.x * 32u + sub], a0);
        a1 = __hfma2(h2_from_int(e1.w), src[(unsigned)e1.z * 32u + sub], a1);
        a0 = __hfma2(h2_from_int(e2.y), src[(unsigned)e2.x * 32u + sub], a0);
        a1 = __hfma2(h2_from_int(e2.w), src[(unsigned)e2.z * 32u + sub], a1);
        a0 = __hfma2(h2_from_int(e3.y), src[(unsigned)e3.x * 32u + sub], a0);
        a1 = __hfma2(h2_from_int(e3.w), src[(unsigned)e3.z * 32u + sub], a1);
        float2 fa = __half22float2(__hadd2(a0, a1));   // flush fp16 partials each group
        s0 += fa.x; s1 += fa.y;
    }
    unsigned o = (unsigned)row * 32u + sub;
    if (last) {
        float2 f0 = __half22float2(c0[o]);
        float2 f1 = __half22float2(c1[o]);
        float2 f2 = __half22float2(src[o]);
        float2 rr;
        rr.x = (f0.x + f1.x + f2.x + s0) * 0.25f;
        rr.y = (f0.y + f1.y + f2.y + s1) * 0.25f;
        reinterpret_cast<float2*>(acc)[o] = rr;
    } else {
        dst[o] = __floats2half2_rn(s0, s1);
    }
}

// ---------------- fallback (fp32 atomic path, used only if ws too small) ----------------

__global__ void initf_kernel(const float* __restrict__ user_emb,
                             const float* __restrict__ item_emb,
                             float* __restrict__ cur,
                             float* __restrict__ acc) {
    int i = blockIdx.x * blockDim.x + threadIdx.x;
    const int total = N_TOT * DIM;
    if (i < total) {
        float v = (i < N_USERS * DIM) ? user_emb[i] : item_emb[i - N_USERS * DIM];
        cur[i] = v;
        acc[i] = v;
    }
}

__global__ void zero_f_kernel(float* __restrict__ p, int n) {
    int i = blockIdx.x * blockDim.x + threadIdx.x;
    if (i < n) p[i] = 0.0f;
}

__global__ void spmm_atomic_kernel(const int* __restrict__ rows, const int* __restrict__ cols,
                                   const float* __restrict__ vals,
                                   const float* __restrict__ cur, float* __restrict__ next) {
    int tid = blockIdx.x * blockDim.x + threadIdx.x;
    int e = tid >> 4;
    int q = (tid & 15) << 2;
    if (e < E_EDGES) {
        int r = rows[e];
        int c = cols[e];
        float v = vals[e];
        const float4 x = *reinterpret_cast<const float4*>(cur + (size_t)c * DIM + q);
        float* dstp = next + (size_t)r * DIM + q;
        atomicAdd(dstp + 0, v * x.x);
        atomicAdd(dstp + 1, v * x.y);
        atomicAdd(dstp + 2, v * x.z);
        atomicAdd(dstp + 3, v * x.w);
    }
}

__global__ void accum_kernel(float* __restrict__ acc, const float* __restrict__ next, int n) {
    int i = blockIdx.x * blockDim.x + threadIdx.x;
    if (i < n) acc[i] += next[i];
}

__global__ void scale_kernel(float* __restrict__ acc, int n) {
    int i = blockIdx.x * blockDim.x + threadIdx.x;
    if (i < n) acc[i] *= 0.25f;
}

// ---------------- launch ----------------

extern "C" void kernel_launch(void* const* d_in, const int* in_sizes, int n_in,
                              void* d_out, int out_size, void* d_ws, size_t ws_size,
                              hipStream_t stream) {
    const int*   rows     = (const int*)d_in[0];
    const int*   cols     = (const int*)d_in[1];
    const float* vals     = (const float*)d_in[2];
    const float* user_emb = (const float*)d_in[3];
    const float* item_emb = (const float*)d_in[4];
    float* acc = (float*)d_out;

    const int total  = N_TOT * DIM;
    const int total2 = total / 2;          // half2 count per buffer
    const int tb = 256;

    // workspace layout; tmp (24 MB) overlays b0+b1 (38.4 MB) — tmp dead
    // before init_kernel writes b0 (init runs after sort_kernel).
    __half2* b0 = (__half2*)d_ws;
    __half2* b1 = b0 + (size_t)total2;
    __half2* b2 = b1 + (size_t)total2;
    int2* tmp   = (int2*)d_ws;
    int2* sedge = (int2*)(b2 + (size_t)total2);
    int* row_ptr = (int*)(sedge + (size_t)SEDGE_MAX);
    int* rowdeg  = row_ptr + NP1;
    int* fill1   = rowdeg + N_TOT;          // contiguous with rowdeg for one zero pass
    int* bktraw  = fill1 + NB1;
    int* bktpad  = bktraw + NB1;
    int* bstart  = bktpad + NB1;            // NB1+1
    int* pbstart = bstart + NB1 + 1;        // NB1+1
    size_t need = (size_t)((char*)(pbstart + NB1 + 1) - (char*)d_ws);

    const int grid_bin = (E_EDGES + EPB - 1) / EPB;  // 733

    if (ws_size >= need) {
        zero_int_kernel<<<(N_TOT + NB1 + tb - 1) / tb, tb, 0, stream>>>(rowdeg, N_TOT + NB1);
        rowhist_kernel<<<(E_EDGES + tb - 1) / tb, tb, 0, stream>>>(rows, rowdeg);
        bucketsum_kernel<<<NB1, tb, 0, stream>>>(rowdeg, bktraw, bktpad);
        bscan2_kernel<<<1, tb, 0, stream>>>(bktraw, bktpad, bstart, pbstart);
        rowptr_kernel<<<NB1, tb, 0, stream>>>(rowdeg, pbstart, row_ptr, sedge);
        bin_kernel<<<grid_bin, tb, 0, stream>>>(rows, cols, vals, bstart, fill1, tmp);
        sort_kernel<<<NB1, tb, 0, stream>>>(tmp, bstart, row_ptr, sedge);

        dim3 blkInit((total / 4 + tb - 1) / tb);
        init_kernel<<<blkInit, tb, 0, stream>>>(user_emb, item_emb, b0);

        const int waves = N_TOT / 2;                 // 75000
        dim3 blkRows((waves * 64 + tb - 1) / tb);    // 18750
        spmm2_kernel<<<blkRows, tb, 0, stream>>>(row_ptr, sedge, b0, b1, b0, b0, acc, 0);
        spmm2_kernel<<<blkRows, tb, 0, stream>>>(row_ptr, sedge, b1, b2, b0, b0, acc, 0);
        spmm2_kernel<<<blkRows, tb, 0, stream>>>(row_ptr, sedge, b2, b2, b0, b1, acc, 1);
    } else {
        // fallback: fp32 atomic scatter path
        float* fcur = (float*)d_ws;
        float* fnxt = fcur + (size_t)total;
        dim3 blkTotal((total + tb - 1) / tb);
        initf_kernel<<<blkTotal, tb, 0, stream>>>(user_emb, item_emb, fcur, acc);
        const long long spmm_threads = (long long)E_EDGES * 16;
        dim3 blkSpmm((unsigned)((spmm_threads + tb - 1) / tb));
        for (int layer = 0; layer < 3; ++layer) {
            zero_f_kernel<<<blkTotal, tb, 0, stream>>>(fnxt, total);
            spmm_atomic_kernel<<<blkSpmm, tb, 0, stream>>>(rows, cols, vals, fcur, fnxt);
            accum_kernel<<<blkTotal, tb, 0, stream>>>(acc, fnxt, total);
            float* t = fcur; fcur = fnxt; fnxt = t;
        }
        scale_kernel<<<blkTotal, tb, 0, stream>>>(acc, total);
    }
}

// Round 8
// 299.399 us; speedup vs baseline: 1.2887x; 1.2887x over previous
//
#include <hip/hip_runtime.h>
#include <hip/hip_fp16.h>

#define N_USERS 100000
#define N_ITEMS 50000
#define N_TOT   150000
#define DIM     64
#define E_EDGES 3000000
#define NP1     (N_TOT + 1)
#define NB1     586          // ceil(150000/256) coarse buckets (row >> 8)
#define EPB     4096         // edges per block in binning kernels
#define SEDGE_MAX 4100000    // E + 7*N_TOT padded worst case

__device__ __forceinline__ __half2 h2_from_int(int x) {
    union { int i; __half2 h; } u; u.i = x; return u.h;
}
__device__ __forceinline__ int int_from_h2(__half2 h) {
    union { int i; __half2 h; } u; u.h = h; return u.i;
}

// ---------------- init: b0 = fp16(emb) ----------------

__global__ void init_kernel(const float* __restrict__ user_emb,
                            const float* __restrict__ item_emb,
                            __half2* __restrict__ b0) {
    int i = blockIdx.x * blockDim.x + threadIdx.x;
    const int total4 = N_TOT * DIM / 4;
    if (i < total4) {
        int base = i * 4;
        float4 v = (base < N_USERS * DIM)
                     ? reinterpret_cast<const float4*>(user_emb)[i]
                     : reinterpret_cast<const float4*>(item_emb)[(base - N_USERS * DIM) >> 2];
        b0[i * 2]     = __floats2half2_rn(v.x, v.y);
        b0[i * 2 + 1] = __floats2half2_rn(v.z, v.w);
    }
}

__global__ void zero_int_kernel(int* __restrict__ p, int n) {
    int i = blockIdx.x * blockDim.x + threadIdx.x;
    if (i < n) p[i] = 0;
}

// ---------------- CSR build ----------------

// coarse-bucket histogram (LDS-staged)
__global__ __launch_bounds__(256) void hist1_kernel(const int* __restrict__ rows,
                                                    int* __restrict__ hist1) {
    __shared__ int h[NB1];
    for (int b = threadIdx.x; b < NB1; b += 256) h[b] = 0;
    __syncthreads();
    int e0 = blockIdx.x * EPB;
    int cnt = min(EPB, E_EDGES - e0);
    for (int i = threadIdx.x; i < cnt; i += 256)
        atomicAdd(&h[rows[e0 + i] >> 8], 1);
    __syncthreads();
    for (int b = threadIdx.x; b < NB1; b += 256)
        if (h[b]) atomicAdd(&hist1[b], h[b]);
}

// single-block exclusive scan over NB1 counters -> dst[0..NB1]
__global__ __launch_bounds__(256) void scan586_kernel(const int* __restrict__ src,
                                                      int* __restrict__ dst) {
    __shared__ int psum[256];
    int t = threadIdx.x;
    int i0 = t * 3;
    int s0 = (i0     < NB1) ? src[i0]     : 0;
    int s1 = (i0 + 1 < NB1) ? src[i0 + 1] : 0;
    int s2 = (i0 + 2 < NB1) ? src[i0 + 2] : 0;
    int tsum = s0 + s1 + s2;
    psum[t] = tsum;
    __syncthreads();
    for (int off = 1; off < 256; off <<= 1) {
        int x = (t >= off) ? psum[t - off] : 0;
        __syncthreads();
        psum[t] += x;
        __syncthreads();
    }
    int excl = psum[t] - tsum;
    if (i0     < NB1) dst[i0]     = excl;
    if (i0 + 1 < NB1) dst[i0 + 1] = excl + s0;
    if (i0 + 2 < NB1) dst[i0 + 2] = excl + s0 + s1;
    if (t == 255) dst[NB1] = psum[255];
}

// bin edges into coarse buckets (LDS-staged, coalesced run write-out)
__global__ __launch_bounds__(256) void bin_kernel(const int* __restrict__ rows,
                                                  const int* __restrict__ cols,
                                                  const float* __restrict__ vals,
                                                  const int* __restrict__ bstart,
                                                  int* __restrict__ fill1,
                                                  int2* __restrict__ tmp) {
    __shared__ int sw0[EPB];
    __shared__ int sw1[EPB];
    __shared__ unsigned short sbkt[EPB];
    __shared__ int hist[NB1];
    __shared__ int sstart[NB1];
    __shared__ int gbase[NB1];
    __shared__ int cursor[NB1];
    __shared__ int psum[256];

    int e0 = blockIdx.x * EPB;
    int cnt = min(EPB, E_EDGES - e0);

    for (int b = threadIdx.x; b < NB1; b += 256) hist[b] = 0;
    __syncthreads();

    int r[16], c[16]; float v[16];
#pragma unroll
    for (int k = 0; k < 16; ++k) {
        int i = threadIdx.x + k * 256;   // coalesced
        r[k] = -1;
        if (i < cnt) {
            int e = e0 + i;
            r[k] = rows[e];
            c[k] = cols[e];
            v[k] = vals[e];
            atomicAdd(&hist[r[k] >> 8], 1);
        }
    }
    __syncthreads();

    int t = threadIdx.x;
    int i0 = t * 3;
    int s0 = (i0     < NB1) ? hist[i0]     : 0;
    int s1 = (i0 + 1 < NB1) ? hist[i0 + 1] : 0;
    int s2 = (i0 + 2 < NB1) ? hist[i0 + 2] : 0;
    int tsum = s0 + s1 + s2;
    psum[t] = tsum;
    __syncthreads();
    for (int off = 1; off < 256; off <<= 1) {
        int x = (t >= off) ? psum[t - off] : 0;
        __syncthreads();
        psum[t] += x;
        __syncthreads();
    }
    int excl = psum[t] - tsum;
    if (i0     < NB1) sstart[i0]     = excl;
    if (i0 + 1 < NB1) sstart[i0 + 1] = excl + s0;
    if (i0 + 2 < NB1) sstart[i0 + 2] = excl + s0 + s1;
    __syncthreads();

    for (int b = threadIdx.x; b < NB1; b += 256) {
        int h = hist[b];
        gbase[b] = (h > 0) ? (bstart[b] + atomicAdd(&fill1[b], h)) : 0;
        cursor[b] = sstart[b];
    }
    __syncthreads();

#pragma unroll
    for (int k = 0; k < 16; ++k) {
        if (r[k] >= 0) {
            int b = r[k] >> 8;
            int p = atomicAdd(&cursor[b], 1);
            sw0[p] = ((r[k] & 0xFF) << 24) | c[k];
            sw1[p] = int_from_h2(__floats2half2_rn(v[k], v[k]));  // duplicated half2 val
            sbkt[p] = (unsigned short)b;
        }
    }
    __syncthreads();

    for (int i = threadIdx.x; i < cnt; i += 256) {
        int b = sbkt[i];
        int dest = gbase[b] + (i - sstart[b]);
        tmp[dest] = make_int2(sw0[i], sw1[i]);
    }
}

// per-bucket row histogram from binned tmp (LDS): rowdeg coalesced + padded total
__global__ __launch_bounds__(256) void bukhist_kernel(const int2* __restrict__ tmp,
                                                      const int* __restrict__ bstart,
                                                      int* __restrict__ rowdeg,
                                                      int* __restrict__ bktpad) {
    int b = blockIdx.x;
    int beg = bstart[b], end = bstart[b + 1];
    __shared__ int hist[256];
    __shared__ int sp[256];
    int t = threadIdx.x;
    hist[t] = 0;
    __syncthreads();
    for (int i = beg + t; i < end; i += 256)
        atomicAdd(&hist[((unsigned)tmp[i].x) >> 24], 1);
    __syncthreads();
    int d = hist[t];
    int r = b * 256 + t;
    if (r < N_TOT) rowdeg[r] = d;
    sp[t] = (d + 7) & ~7;
    __syncthreads();
    for (int off = 128; off > 0; off >>= 1) {
        if (t < off) sp[t] += sp[t + off];
        __syncthreads();
    }
    if (t == 0) bktpad[b] = sp[0];
}

// row_ptr from padded within-bucket scan; zero-fill pad slots in sedge
__global__ __launch_bounds__(256) void rowptr_kernel(const int* __restrict__ rowdeg,
                                                     const int* __restrict__ pbstart,
                                                     int* __restrict__ row_ptr,
                                                     int2* __restrict__ sedge) {
    int b = blockIdx.x, t = threadIdx.x;
    int r = b * 256 + t;
    int d = (r < N_TOT) ? rowdeg[r] : 0;
    int pd = (d + 7) & ~7;
    __shared__ int scn[256];
    scn[t] = pd;
    __syncthreads();
    for (int off = 1; off < 256; off <<= 1) {
        int x = (t >= off) ? scn[t - off] : 0;
        __syncthreads();
        scn[t] += x;
        __syncthreads();
    }
    int excl = scn[t] - pd;
    int rp = pbstart[b] + excl;
    if (r <= N_TOT) row_ptr[r] = rp;
    if (r < N_TOT) {
        int2* spad = sedge + rp + d;
        for (int i = d; i < pd; ++i) *spad++ = make_int2(0, 0);
    }
}

// per-bucket scatter to padded positions; cursors preloaded from row_ptr
__global__ __launch_bounds__(256) void sort_kernel(const int2* __restrict__ tmp,
                                                   const int* __restrict__ bstart,
                                                   const int* __restrict__ row_ptr,
                                                   int2* __restrict__ sedge) {
    int b = blockIdx.x;
    int beg = bstart[b], end = bstart[b + 1];
    __shared__ int cursor[256];
    int t = threadIdx.x;
    int r = b * 256 + t;
    cursor[t] = (r < N_TOT) ? row_ptr[r] : 0;
    __syncthreads();
    for (int i = beg + t; i < end; i += 256) {
        int2 rec = tmp[i];
        int lr = ((unsigned)rec.x) >> 24;
        int p = atomicAdd(&cursor[lr], 1);
        sedge[p] = make_int2(rec.x & 0xFFFFFF, rec.y);
    }
}

// ---------------- SpMM: 2 rows/wave, direct uniform edge loads, pk_fma_f16 ----------------

__global__ __launch_bounds__(256) void spmm2_kernel(const int* __restrict__ row_ptr,
                                                    const int2* __restrict__ sedge,
                                                    const __half2* __restrict__ src,
                                                    __half2* __restrict__ dst,
                                                    const __half2* __restrict__ c0,
                                                    const __half2* __restrict__ c1,
                                                    float* __restrict__ acc,
                                                    int last) {
    int wid2 = (blockIdx.x * blockDim.x + threadIdx.x) >> 6;
    int lane = threadIdx.x & 63;
    int sub = lane & 31;
    int row = wid2 * 2 + (lane >> 5);
    if (row >= N_TOT) return;
    int beg = row_ptr[row];
    int ng  = (row_ptr[row + 1] - beg) >> 3;   // groups of 8 (exact: padded)
    const int4* ep = reinterpret_cast<const int4*>(sedge + beg);
    float s0 = 0.0f, s1 = 0.0f;
    const __half2 z2 = __floats2half2_rn(0.0f, 0.0f);
    for (int g = 0; g < ng; ++g) {
        int4 e0 = ep[0]; int4 e1 = ep[1]; int4 e2 = ep[2]; int4 e3 = ep[3];
        ep += 4;
        __half2 a0 = z2, a1 = z2;
        a0 = __hfma2(h2_from_int(e0.y), src[(unsigned)e0.x * 32u + sub], a0);
        a1 = __hfma2(h2_from_int(e0.w), src[(unsigned)e0.z * 32u + sub], a1);
        a0 = __hfma2(h2_from_int(e1.y), src[(unsigned)e1.x * 32u + sub], a0);
        a1 = __hfma2(h2_from_int(e1.w), src[(unsigned)e1.z * 32u + sub], a1);
        a0 = __hfma2(h2_from_int(e2.y), src[(unsigned)e2.x * 32u + sub], a0);
        a1 = __hfma2(h2_from_int(e2.w), src[(unsigned)e2.z * 32u + sub], a1);
        a0 = __hfma2(h2_from_int(e3.y), src[(unsigned)e3.x * 32u + sub], a0);
        a1 = __hfma2(h2_from_int(e3.w), src[(unsigned)e3.z * 32u + sub], a1);
        float2 fa = __half22float2(__hadd2(a0, a1));   // flush fp16 partials each group
        s0 += fa.x; s1 += fa.y;
    }
    unsigned o = (unsigned)row * 32u + sub;
    if (last) {
        float2 f0 = __half22float2(c0[o]);
        float2 f1 = __half22float2(c1[o]);
        float2 f2 = __half22float2(src[o]);
        float2 rr;
        rr.x = (f0.x + f1.x + f2.x + s0) * 0.25f;
        rr.y = (f0.y + f1.y + f2.y + s1) * 0.25f;
        reinterpret_cast<float2*>(acc)[o] = rr;
    } else {
        dst[o] = __floats2half2_rn(s0, s1);
    }
}

// ---------------- fallback (fp32 atomic path, used only if ws too small) ----------------

__global__ void initf_kernel(const float* __restrict__ user_emb,
                             const float* __restrict__ item_emb,
                             float* __restrict__ cur,
                             float* __restrict__ acc) {
    int i = blockIdx.x * blockDim.x + threadIdx.x;
    const int total = N_TOT * DIM;
    if (i < total) {
        float v = (i < N_USERS * DIM) ? user_emb[i] : item_emb[i - N_USERS * DIM];
        cur[i] = v;
        acc[i] = v;
    }
}

__global__ void zero_f_kernel(float* __restrict__ p, int n) {
    int i = blockIdx.x * blockDim.x + threadIdx.x;
    if (i < n) p[i] = 0.0f;
}

__global__ void spmm_atomic_kernel(const int* __restrict__ rows, const int* __restrict__ cols,
                                   const float* __restrict__ vals,
                                   const float* __restrict__ cur, float* __restrict__ next) {
    int tid = blockIdx.x * blockDim.x + threadIdx.x;
    int e = tid >> 4;
    int q = (tid & 15) << 2;
    if (e < E_EDGES) {
        int r = rows[e];
        int c = cols[e];
        float v = vals[e];
        const float4 x = *reinterpret_cast<const float4*>(cur + (size_t)c * DIM + q);
        float* dstp = next + (size_t)r * DIM + q;
        atomicAdd(dstp + 0, v * x.x);
        atomicAdd(dstp + 1, v * x.y);
        atomicAdd(dstp + 2, v * x.z);
        atomicAdd(dstp + 3, v * x.w);
    }
}

__global__ void accum_kernel(float* __restrict__ acc, const float* __restrict__ next, int n) {
    int i = blockIdx.x * blockDim.x + threadIdx.x;
    if (i < n) acc[i] += next[i];
}

__global__ void scale_kernel(float* __restrict__ acc, int n) {
    int i = blockIdx.x * blockDim.x + threadIdx.x;
    if (i < n) acc[i] *= 0.25f;
}

// ---------------- launch ----------------

extern "C" void kernel_launch(void* const* d_in, const int* in_sizes, int n_in,
                              void* d_out, int out_size, void* d_ws, size_t ws_size,
                              hipStream_t stream) {
    const int*   rows     = (const int*)d_in[0];
    const int*   cols     = (const int*)d_in[1];
    const float* vals     = (const float*)d_in[2];
    const float* user_emb = (const float*)d_in[3];
    const float* item_emb = (const float*)d_in[4];
    float* acc = (float*)d_out;

    const int total  = N_TOT * DIM;
    const int total2 = total / 2;          // half2 count per buffer
    const int tb = 256;

    // workspace layout; tmp (24 MB) overlays b0+b1 (38.4 MB) — tmp dead
    // before init_kernel writes b0 (init runs after sort_kernel).
    __half2* b0 = (__half2*)d_ws;
    __half2* b1 = b0 + (size_t)total2;
    __half2* b2 = b1 + (size_t)total2;
    int2* tmp   = (int2*)d_ws;
    int2* sedge = (int2*)(b2 + (size_t)total2);
    int* row_ptr = (int*)(sedge + (size_t)SEDGE_MAX);
    int* rowdeg  = row_ptr + NP1;
    int* hist1   = rowdeg + N_TOT;
    int* fill1   = hist1 + NB1;             // adjacent to hist1: one zero pass
    int* bktpad  = fill1 + NB1;
    int* bstart  = bktpad + NB1;            // NB1+1
    int* pbstart = bstart + NB1 + 1;        // NB1+1
    size_t need = (size_t)((char*)(pbstart + NB1 + 1) - (char*)d_ws);

    const int grid_bin = (E_EDGES + EPB - 1) / EPB;  // 733

    if (ws_size >= need) {
        zero_int_kernel<<<(2 * NB1 + tb - 1) / tb, tb, 0, stream>>>(hist1, 2 * NB1);
        hist1_kernel<<<grid_bin, tb, 0, stream>>>(rows, hist1);
        scan586_kernel<<<1, tb, 0, stream>>>(hist1, bstart);
        bin_kernel<<<grid_bin, tb, 0, stream>>>(rows, cols, vals, bstart, fill1, tmp);
        bukhist_kernel<<<NB1, tb, 0, stream>>>(tmp, bstart, rowdeg, bktpad);
        scan586_kernel<<<1, tb, 0, stream>>>(bktpad, pbstart);
        rowptr_kernel<<<NB1, tb, 0, stream>>>(rowdeg, pbstart, row_ptr, sedge);
        sort_kernel<<<NB1, tb, 0, stream>>>(tmp, bstart, row_ptr, sedge);

        dim3 blkInit((total / 4 + tb - 1) / tb);
        init_kernel<<<blkInit, tb, 0, stream>>>(user_emb, item_emb, b0);

        const int waves = N_TOT / 2;                 // 75000
        dim3 blkRows((waves * 64 + tb - 1) / tb);    // 18750
        spmm2_kernel<<<blkRows, tb, 0, stream>>>(row_ptr, sedge, b0, b1, b0, b0, acc, 0);
        spmm2_kernel<<<blkRows, tb, 0, stream>>>(row_ptr, sedge, b1, b2, b0, b0, acc, 0);
        spmm2_kernel<<<blkRows, tb, 0, stream>>>(row_ptr, sedge, b2, b2, b0, b1, acc, 1);
    } else {
        // fallback: fp32 atomic scatter path
        float* fcur = (float*)d_ws;
        float* fnxt = fcur + (size_t)total;
        dim3 blkTotal((total + tb - 1) / tb);
        initf_kernel<<<blkTotal, tb, 0, stream>>>(user_emb, item_emb, fcur, acc);
        const long long spmm_threads = (long long)E_EDGES * 16;
        dim3 blkSpmm((unsigned)((spmm_threads + tb - 1) / tb));
        for (int layer = 0; layer < 3; ++layer) {
            zero_f_kernel<<<blkTotal, tb, 0, stream>>>(fnxt, total);
            spmm_atomic_kernel<<<blkSpmm, tb, 0, stream>>>(rows, cols, vals, fcur, fnxt);
            accum_kernel<<<blkTotal, tb, 0, stream>>>(acc, fnxt, total);
            float* t = fcur; fcur = fnxt; fnxt = t;
        }
        scale_kernel<<<blkTotal, tb, 0, stream>>>(acc, total);
    }
}